// Round 1
// baseline (5679.324 us; speedup 1.0000x reference)
//
#include <hip/hip_runtime.h>

namespace {
constexpr int kNT = 200000;
constexpr int kNM = 20000;
constexpr int kE  = 1000000;

__global__ void degree_kernel(const int* __restrict__ tm_dst,
                              const int* __restrict__ mt_dst,
                              float* __restrict__ deg_m,
                              float* __restrict__ deg_t) {
  int stride = gridDim.x * blockDim.x;
  for (int e = blockIdx.x * blockDim.x + threadIdx.x; e < kE; e += stride) {
    atomicAdd(&deg_m[tm_dst[e]], 1.0f);
    atomicAdd(&deg_t[mt_dst[e]], 1.0f);
  }
}

// One float4 chunk per thread; DV4 = D/4 (power of two).
template <int DV4>
__global__ void scatter_add_kernel(const float4* __restrict__ x,
                                   const int* __restrict__ src,
                                   const int* __restrict__ dst,
                                   float* __restrict__ agg) {
  const long long total = (long long)kE * DV4;
  const long long stride = (long long)gridDim.x * blockDim.x;
  for (long long i = (long long)blockIdx.x * blockDim.x + threadIdx.x; i < total;
       i += stride) {
    const int e = (int)(i / DV4);
    const int c = (int)(i % DV4);
    const int s = src[e];
    const int d = dst[e];
    const float4 v = x[(long long)s * DV4 + c];
    float* o = agg + (long long)d * (DV4 * 4) + c * 4;
    atomicAdd(o + 0, v.x);
    atomicAdd(o + 1, v.y);
    atomicAdd(o + 2, v.z);
    atomicAdd(o + 3, v.w);
  }
}

// h[row, j] = lrelu( (agg[row,:]/max(deg,1)) @ Wl[:,j] + bl[j] + xdst[row,:] @ Wr[:,j] )
// Optionally fused classifier head (OUT=2) via wave reduction.
template <int KL, int KR, bool HEAD>
__global__ __launch_bounds__(256) void node_kernel(
    const float* __restrict__ agg, const float* __restrict__ deg,
    const float* __restrict__ xdst, const float* __restrict__ Wl,
    const float* __restrict__ bl, const float* __restrict__ Wr,
    float* __restrict__ hout, int n, const float* __restrict__ Wout,
    const float* __restrict__ bout, float* __restrict__ head_out) {
  __shared__ float sWl[KL * 64];
  __shared__ float sWr[KR * 64];
  const int t = threadIdx.x;
  for (int i = t; i < KL * 64; i += 256) sWl[i] = Wl[i];
  for (int i = t; i < KR * 64; i += 256) sWr[i] = Wr[i];
  __syncthreads();
  const int j = t & 63;   // output column (lane)
  const int r = t >> 6;   // row within block tile (one wave per row)
  const float blj = bl[j];
  for (int row = blockIdx.x * 4 + r; row < n; row += gridDim.x * 4) {
    const float4* __restrict__ a4 = (const float4*)(agg + (long long)row * KL);
    const float4* __restrict__ x4 = (const float4*)(xdst + (long long)row * KR);
    float accl = 0.f;
#pragma unroll
    for (int k4 = 0; k4 < KL / 4; ++k4) {
      const float4 v = a4[k4];
      accl += v.x * sWl[(k4 * 4 + 0) * 64 + j];
      accl += v.y * sWl[(k4 * 4 + 1) * 64 + j];
      accl += v.z * sWl[(k4 * 4 + 2) * 64 + j];
      accl += v.w * sWl[(k4 * 4 + 3) * 64 + j];
    }
    float acc = accl / fmaxf(deg[row], 1.0f) + blj;
#pragma unroll
    for (int k4 = 0; k4 < KR / 4; ++k4) {
      const float4 v = x4[k4];
      acc += v.x * sWr[(k4 * 4 + 0) * 64 + j];
      acc += v.y * sWr[(k4 * 4 + 1) * 64 + j];
      acc += v.z * sWr[(k4 * 4 + 2) * 64 + j];
      acc += v.w * sWr[(k4 * 4 + 3) * 64 + j];
    }
    const float h = acc >= 0.f ? acc : 0.01f * acc;
    hout[(long long)row * 64 + j] = h;
    if (HEAD) {
      float s0 = h * Wout[j * 2 + 0];
      float s1 = h * Wout[j * 2 + 1];
#pragma unroll
      for (int off = 32; off > 0; off >>= 1) {
        s0 += __shfl_xor(s0, off, 64);
        s1 += __shfl_xor(s1, off, 64);
      }
      if (j == 0) {
        head_out[(long long)row * 2 + 0] = s0 + bout[0];
        head_out[(long long)row * 2 + 1] = s1 + bout[1];
      }
    }
  }
}
}  // namespace

extern "C" void kernel_launch(void* const* d_in, const int* in_sizes, int n_in,
                              void* d_out, int out_size, void* d_ws, size_t ws_size,
                              hipStream_t stream) {
  const float* x_trans = (const float*)d_in[0];
  const float* x_merch = (const float*)d_in[1];
  const int* tm_src = (const int*)d_in[2];
  const int* tm_dst = (const int*)d_in[3];
  const int* mt_src = (const int*)d_in[4];
  const int* mt_dst = (const int*)d_in[5];
  const float* Wl_tm1 = (const float*)d_in[6];
  const float* bl_tm1 = (const float*)d_in[7];
  const float* Wr_tm1 = (const float*)d_in[8];
  const float* Wl_mt1 = (const float*)d_in[9];
  const float* bl_mt1 = (const float*)d_in[10];
  const float* Wr_mt1 = (const float*)d_in[11];
  const float* Wl_tm2 = (const float*)d_in[12];
  const float* bl_tm2 = (const float*)d_in[13];
  const float* Wr_tm2 = (const float*)d_in[14];
  const float* Wl_mt2 = (const float*)d_in[15];
  const float* bl_mt2 = (const float*)d_in[16];
  const float* Wr_mt2 = (const float*)d_in[17];
  const float* W_out = (const float*)d_in[18];
  const float* b_out = (const float*)d_in[19];

  float* out_head = (float*)d_out;                    // [N_T, 2]
  float* h_t2 = (float*)d_out + (long long)kNT * 2;   // [N_T, 64]

  float* ws = (float*)d_ws;
  long long off = 0;
  auto alloc = [&](long long nfloats) {
    float* p = ws + off;
    off += (nfloats + 1023) & ~1023LL;
    return p;
  };
  float* deg_m = alloc(kNM);
  float* deg_t = alloc(kNT);
  float* agg_m = alloc((long long)kNM * 128);  // layer1 tm agg; reused (stride 64) in layer2
  float* agg_t = alloc((long long)kNT * 64);   // layer1 mt agg; reused in layer2
  float* h_m = alloc((long long)kNM * 64);
  float* h_t = alloc((long long)kNT * 64);
  float* h_m2 = alloc((long long)kNM * 64);

  // Zero degrees + layer-1 agg buffers (contiguous at front of ws).
  const size_t zero1 = (size_t)((agg_t + (long long)kNT * 64) - ws) * sizeof(float);
  hipMemsetAsync(d_ws, 0, zero1, stream);

  degree_kernel<<<2048, 256, 0, stream>>>(tm_dst, mt_dst, deg_m, deg_t);

  // Layer 1 aggregation.
  scatter_add_kernel<32><<<4096, 256, 0, stream>>>((const float4*)x_trans, tm_src,
                                                   tm_dst, agg_m);
  scatter_add_kernel<16><<<4096, 256, 0, stream>>>((const float4*)x_merch, mt_src,
                                                   mt_dst, agg_t);

  // Layer 1 node updates.
  node_kernel<128, 64, false><<<(kNM + 3) / 4, 256, 0, stream>>>(
      agg_m, deg_m, x_merch, Wl_tm1, bl_tm1, Wr_tm1, h_m, kNM, nullptr, nullptr,
      nullptr);
  node_kernel<64, 128, false><<<(kNT + 3) / 4, 256, 0, stream>>>(
      agg_t, deg_t, x_trans, Wl_mt1, bl_mt1, Wr_mt1, h_t, kNT, nullptr, nullptr,
      nullptr);

  // Re-zero agg buffers for layer 2.
  const size_t zoff = (size_t)(agg_m - ws) * sizeof(float);
  const size_t zlen =
      (size_t)((agg_t + (long long)kNT * 64) - agg_m) * sizeof(float);
  hipMemsetAsync((char*)d_ws + zoff, 0, zlen, stream);

  // Layer 2 aggregation (agg_m reused with row stride 64).
  scatter_add_kernel<16><<<4096, 256, 0, stream>>>((const float4*)h_t, tm_src,
                                                   tm_dst, agg_m);
  scatter_add_kernel<16><<<4096, 256, 0, stream>>>((const float4*)h_m, mt_src,
                                                   mt_dst, agg_t);

  // Layer 2 node updates (+ fused classifier head on transactions).
  node_kernel<64, 64, false><<<(kNM + 3) / 4, 256, 0, stream>>>(
      agg_m, deg_m, h_m, Wl_tm2, bl_tm2, Wr_tm2, h_m2, kNM, nullptr, nullptr,
      nullptr);
  node_kernel<64, 64, true><<<(kNT + 3) / 4, 256, 0, stream>>>(
      agg_t, deg_t, h_t, Wl_mt2, bl_mt2, Wr_mt2, h_t2, kNT, W_out, b_out,
      out_head);
}

// Round 2
// 1703.744 us; speedup vs baseline: 3.3334x; 3.3334x over previous
//
#include <hip/hip_runtime.h>

namespace {
constexpr int kNT = 200000;
constexpr int kNM = 20000;
constexpr int kE  = 1000000;

// --- CSR build ---------------------------------------------------------------

__global__ void hist_kernel(const int* __restrict__ tm_dst,
                            const int* __restrict__ mt_dst,
                            int* __restrict__ cnt_m, int* __restrict__ cnt_t) {
  int stride = gridDim.x * blockDim.x;
  for (int e = blockIdx.x * blockDim.x + threadIdx.x; e < kE; e += stride) {
    atomicAdd(&cnt_m[tm_dst[e]], 1);
    atomicAdd(&cnt_t[mt_dst[e]], 1);
  }
}

// Per-block exclusive scan over chunks of 1024 (256 thr x 4). Safe with out==in.
__global__ __launch_bounds__(256) void scan_blocks_kernel(
    const int* __restrict__ in, int n, int* __restrict__ out,
    int* __restrict__ partials) {
  __shared__ int lds[256];
  const int t = threadIdx.x;
  const int base = blockIdx.x * 1024;
  int v[4];
  int s = 0;
#pragma unroll
  for (int k = 0; k < 4; ++k) {
    int idx = base + t * 4 + k;
    v[k] = (idx < n) ? in[idx] : 0;
    s += v[k];
  }
  int x = s;
  lds[t] = x;
  __syncthreads();
  for (int off = 1; off < 256; off <<= 1) {
    int y = (t >= off) ? lds[t - off] : 0;
    __syncthreads();
    x += y;
    lds[t] = x;
    __syncthreads();
  }
  if (t == 255) partials[blockIdx.x] = x;
  int run = x - s;  // exclusive prefix of this thread's chunk
#pragma unroll
  for (int k = 0; k < 4; ++k) {
    int idx = base + t * 4 + k;
    if (idx < n) out[idx] = run;
    run += v[k];
  }
}

// Single block; nb <= 256. In-place inclusive->exclusive scan of block totals.
__global__ __launch_bounds__(256) void scan_partials_kernel(int* __restrict__ p,
                                                            int nb) {
  __shared__ int lds[256];
  const int t = threadIdx.x;
  int v = (t < nb) ? p[t] : 0;
  int x = v;
  lds[t] = x;
  __syncthreads();
  for (int off = 1; off < 256; off <<= 1) {
    int y = (t >= off) ? lds[t - off] : 0;
    __syncthreads();
    x += y;
    lds[t] = x;
    __syncthreads();
  }
  if (t < nb) p[t] = x - v;
}

__global__ void add_offsets_kernel(const int* __restrict__ scanned,
                                   const int* __restrict__ partials, int n,
                                   int* __restrict__ rp, int* __restrict__ next) {
  int i = blockIdx.x * 256 + threadIdx.x;
  if (i == 0) rp[n] = kE;
  if (i < n) {
    int v = scanned[i] + partials[i >> 10];
    rp[i] = v;
    next[i] = v;
  }
}

__global__ void fill_csr_kernel(const int* __restrict__ src,
                                const int* __restrict__ dst,
                                int* __restrict__ next, int* __restrict__ csr) {
  int stride = gridDim.x * blockDim.x;
  for (int e = blockIdx.x * blockDim.x + threadIdx.x; e < kE; e += stride) {
    int p = atomicAdd(&next[dst[e]], 1);
    csr[p] = src[e];
  }
}

// --- Aggregation: one wave per dst node, mean fused --------------------------

template <int D>
__global__ __launch_bounds__(256) void gather_mean_kernel(
    const float* __restrict__ x, const int* __restrict__ rp,
    const int* __restrict__ csr, float* __restrict__ out, int n) {
  const int lane = threadIdx.x & 63;
  const int node = blockIdx.x * 4 + (threadIdx.x >> 6);
  if (node >= n) return;
  const int beg = rp[node], end = rp[node + 1];
  float acc0 = 0.f, acc1 = 0.f;
  for (int base = beg; base < end; base += 64) {
    const int m = min(64, end - base);
    const int kreg = (base + lane < end) ? csr[base + lane] : 0;
    for (int i = 0; i < m; ++i) {
      const int s = __shfl(kreg, i, 64);
      const float* __restrict__ row = x + (long long)s * D;
      acc0 += row[lane];
      if (D == 128) acc1 += row[64 + lane];
    }
  }
  const float r = 1.0f / fmaxf((float)(end - beg), 1.0f);
  out[(long long)node * D + lane] = acc0 * r;
  if (D == 128) out[(long long)node * D + 64 + lane] = acc1 * r;
}

// --- Node update: h = lrelu(mean@Wl + bl + xdst@Wr), optional fused head -----

template <int KL, int KR, bool HEAD>
__global__ __launch_bounds__(256) void node_kernel(
    const float* __restrict__ agg, const float* __restrict__ xdst,
    const float* __restrict__ Wl, const float* __restrict__ bl,
    const float* __restrict__ Wr, float* __restrict__ hout, int n,
    const float* __restrict__ Wout, const float* __restrict__ bout,
    float* __restrict__ head_out) {
  __shared__ float sWl[KL * 64];
  __shared__ float sWr[KR * 64];
  const int t = threadIdx.x;
  for (int i = t; i < KL * 64; i += 256) sWl[i] = Wl[i];
  for (int i = t; i < KR * 64; i += 256) sWr[i] = Wr[i];
  __syncthreads();
  const int j = t & 63;
  const int r = t >> 6;
  const float blj = bl[j];
  for (int row = blockIdx.x * 4 + r; row < n; row += gridDim.x * 4) {
    const float4* __restrict__ a4 = (const float4*)(agg + (long long)row * KL);
    const float4* __restrict__ x4 = (const float4*)(xdst + (long long)row * KR);
    float acc = blj;
#pragma unroll
    for (int k4 = 0; k4 < KL / 4; ++k4) {
      const float4 v = a4[k4];
      acc += v.x * sWl[(k4 * 4 + 0) * 64 + j];
      acc += v.y * sWl[(k4 * 4 + 1) * 64 + j];
      acc += v.z * sWl[(k4 * 4 + 2) * 64 + j];
      acc += v.w * sWl[(k4 * 4 + 3) * 64 + j];
    }
#pragma unroll
    for (int k4 = 0; k4 < KR / 4; ++k4) {
      const float4 v = x4[k4];
      acc += v.x * sWr[(k4 * 4 + 0) * 64 + j];
      acc += v.y * sWr[(k4 * 4 + 1) * 64 + j];
      acc += v.z * sWr[(k4 * 4 + 2) * 64 + j];
      acc += v.w * sWr[(k4 * 4 + 3) * 64 + j];
    }
    const float h = acc >= 0.f ? acc : 0.01f * acc;
    hout[(long long)row * 64 + j] = h;
    if (HEAD) {
      float s0 = h * Wout[j * 2 + 0];
      float s1 = h * Wout[j * 2 + 1];
#pragma unroll
      for (int off = 32; off > 0; off >>= 1) {
        s0 += __shfl_xor(s0, off, 64);
        s1 += __shfl_xor(s1, off, 64);
      }
      if (j == 0) {
        head_out[(long long)row * 2 + 0] = s0 + bout[0];
        head_out[(long long)row * 2 + 1] = s1 + bout[1];
      }
    }
  }
}
}  // namespace

extern "C" void kernel_launch(void* const* d_in, const int* in_sizes, int n_in,
                              void* d_out, int out_size, void* d_ws, size_t ws_size,
                              hipStream_t stream) {
  const float* x_trans = (const float*)d_in[0];
  const float* x_merch = (const float*)d_in[1];
  const int* tm_src = (const int*)d_in[2];
  const int* tm_dst = (const int*)d_in[3];
  const int* mt_src = (const int*)d_in[4];
  const int* mt_dst = (const int*)d_in[5];
  const float* Wl_tm1 = (const float*)d_in[6];
  const float* bl_tm1 = (const float*)d_in[7];
  const float* Wr_tm1 = (const float*)d_in[8];
  const float* Wl_mt1 = (const float*)d_in[9];
  const float* bl_mt1 = (const float*)d_in[10];
  const float* Wr_mt1 = (const float*)d_in[11];
  // d_in[12..17]: layer-2 tm weights (unused: h_m2 is dead in the reference)
  const float* Wl_mt2 = (const float*)d_in[15];
  const float* bl_mt2 = (const float*)d_in[16];
  const float* Wr_mt2 = (const float*)d_in[17];
  const float* W_out = (const float*)d_in[18];
  const float* b_out = (const float*)d_in[19];

  float* out_head = (float*)d_out;                   // [N_T, 2]
  float* h_t = (float*)d_out + (long long)kNT * 2;   // [N_T, 64]; layer-1 h_t,
                                                     // transformed in-place to h_t2

  char* ws = (char*)d_ws;
  size_t off = 0;
  auto alloc = [&](size_t bytes) {
    char* p = ws + off;
    off = (off + bytes + 255) & ~(size_t)255;
    return p;
  };
  int* cnt_m = (int*)alloc(kNM * 4);        // also holds scanned values
  int* cnt_t = (int*)alloc(kNT * 4);
  int* rp_m = (int*)alloc((kNM + 1) * 4);
  int* rp_t = (int*)alloc((kNT + 1) * 4);
  int* next_m = (int*)alloc(kNM * 4);
  int* next_t = (int*)alloc(kNT * 4);
  int* part_m = (int*)alloc(256 * 4);
  int* part_t = (int*)alloc(256 * 4);
  int* csr_tm = (int*)alloc((size_t)kE * 4);
  int* csr_mt = (int*)alloc((size_t)kE * 4);
  float* agg_m = (float*)alloc((size_t)kNM * 128 * 4);
  float* agg_t = (float*)alloc((size_t)kNT * 64 * 4);  // reused in layer 2
  float* h_m = (float*)alloc((size_t)kNM * 64 * 4);

  // Zero the two count arrays (adjacent at the front of ws).
  hipMemsetAsync(d_ws, 0, (size_t)((char*)(cnt_t + kNT) - ws), stream);

  // CSR build: histogram -> exclusive scan -> slot fill.
  hist_kernel<<<2048, 256, 0, stream>>>(tm_dst, mt_dst, cnt_m, cnt_t);

  const int nbm = (kNM + 1023) / 1024, nbt = (kNT + 1023) / 1024;
  scan_blocks_kernel<<<nbm, 256, 0, stream>>>(cnt_m, kNM, cnt_m, part_m);
  scan_blocks_kernel<<<nbt, 256, 0, stream>>>(cnt_t, kNT, cnt_t, part_t);
  scan_partials_kernel<<<1, 256, 0, stream>>>(part_m, nbm);
  scan_partials_kernel<<<1, 256, 0, stream>>>(part_t, nbt);
  add_offsets_kernel<<<(kNM + 255) / 256, 256, 0, stream>>>(cnt_m, part_m, kNM,
                                                            rp_m, next_m);
  add_offsets_kernel<<<(kNT + 255) / 256, 256, 0, stream>>>(cnt_t, part_t, kNT,
                                                            rp_t, next_t);
  fill_csr_kernel<<<2048, 256, 0, stream>>>(tm_src, tm_dst, next_m, csr_tm);
  fill_csr_kernel<<<2048, 256, 0, stream>>>(mt_src, mt_dst, next_t, csr_mt);

  // Layer 1: gather means, then node updates.
  gather_mean_kernel<128><<<(kNM + 3) / 4, 256, 0, stream>>>(x_trans, rp_m,
                                                             csr_tm, agg_m, kNM);
  gather_mean_kernel<64><<<(kNT + 3) / 4, 256, 0, stream>>>(x_merch, rp_t,
                                                            csr_mt, agg_t, kNT);
  node_kernel<128, 64, false><<<(kNM + 3) / 4, 256, 0, stream>>>(
      agg_m, x_merch, Wl_tm1, bl_tm1, Wr_tm1, h_m, kNM, nullptr, nullptr,
      nullptr);
  node_kernel<64, 128, false><<<(kNT + 3) / 4, 256, 0, stream>>>(
      agg_t, x_trans, Wl_mt1, bl_mt1, Wr_mt1, h_t, kNT, nullptr, nullptr,
      nullptr);

  // Layer 2 (transaction side only; merchant layer-2 output is unused).
  gather_mean_kernel<64><<<(kNT + 3) / 4, 256, 0, stream>>>(h_m, rp_t, csr_mt,
                                                            agg_t, kNT);
  node_kernel<64, 64, true><<<(kNT + 3) / 4, 256, 0, stream>>>(
      agg_t, h_t, Wl_mt2, bl_mt2, Wr_mt2, h_t, kNT, W_out, b_out, out_head);
}

// Round 3
// 1269.835 us; speedup vs baseline: 4.4725x; 1.3417x over previous
//
#include <hip/hip_runtime.h>

namespace {
constexpr int kNT = 200000;
constexpr int kNM = 20000;
constexpr int kE  = 1000000;

// --- CSR build ---------------------------------------------------------------

__global__ void hist_kernel(const int* __restrict__ tm_dst,
                            const int* __restrict__ mt_dst,
                            int* __restrict__ cnt_m, int* __restrict__ cnt_t) {
  int stride = gridDim.x * blockDim.x;
  for (int e = blockIdx.x * blockDim.x + threadIdx.x; e < kE; e += stride) {
    atomicAdd(&cnt_m[tm_dst[e]], 1);
    atomicAdd(&cnt_t[mt_dst[e]], 1);
  }
}

// Per-block exclusive scan over chunks of 1024 (256 thr x 4). Safe with out==in.
__global__ __launch_bounds__(256) void scan_blocks_kernel(
    const int* __restrict__ in, int n, int* __restrict__ out,
    int* __restrict__ partials) {
  __shared__ int lds[256];
  const int t = threadIdx.x;
  const int base = blockIdx.x * 1024;
  int v[4];
  int s = 0;
#pragma unroll
  for (int k = 0; k < 4; ++k) {
    int idx = base + t * 4 + k;
    v[k] = (idx < n) ? in[idx] : 0;
    s += v[k];
  }
  int x = s;
  lds[t] = x;
  __syncthreads();
  for (int off = 1; off < 256; off <<= 1) {
    int y = (t >= off) ? lds[t - off] : 0;
    __syncthreads();
    x += y;
    lds[t] = x;
    __syncthreads();
  }
  if (t == 255) partials[blockIdx.x] = x;
  int run = x - s;  // exclusive prefix of this thread's chunk
#pragma unroll
  for (int k = 0; k < 4; ++k) {
    int idx = base + t * 4 + k;
    if (idx < n) out[idx] = run;
    run += v[k];
  }
}

// Single block; nb <= 256. In-place inclusive->exclusive scan of block totals.
__global__ __launch_bounds__(256) void scan_partials_kernel(int* __restrict__ p,
                                                            int nb) {
  __shared__ int lds[256];
  const int t = threadIdx.x;
  int v = (t < nb) ? p[t] : 0;
  int x = v;
  lds[t] = x;
  __syncthreads();
  for (int off = 1; off < 256; off <<= 1) {
    int y = (t >= off) ? lds[t - off] : 0;
    __syncthreads();
    x += y;
    lds[t] = x;
    __syncthreads();
  }
  if (t < nb) p[t] = x - v;
}

__global__ void add_offsets_kernel(const int* __restrict__ scanned,
                                   const int* __restrict__ partials, int n,
                                   int* __restrict__ rp, int* __restrict__ next) {
  int i = blockIdx.x * 256 + threadIdx.x;
  if (i == 0) rp[n] = kE;
  if (i < n) {
    int v = scanned[i] + partials[i >> 10];
    rp[i] = v;
    next[i] = v;
  }
}

__global__ void fill_csr_kernel(const int* __restrict__ src,
                                const int* __restrict__ dst,
                                int* __restrict__ next, int* __restrict__ csr) {
  int stride = gridDim.x * blockDim.x;
  for (int e = blockIdx.x * blockDim.x + threadIdx.x; e < kE; e += stride) {
    int p = atomicAdd(&next[dst[e]], 1);
    csr[p] = src[e];
  }
}

// --- Fused SAGE layer: gather-mean + lin_l + lin_r + lrelu (+head) -----------
// One wave per dst node; persistent blocks (weights staged once per block).
// Wave gathers neighbor rows coalesced (lane j = feature j), parks the mean in
// a per-wave LDS slot (same-wave ds dep, no barrier), then runs the FMA loop
// with uniform broadcast float4 reads of the mean / self row.
template <int KL, int KR, bool HEAD>
__global__ __launch_bounds__(256) void fused_sage_kernel(
    const float* __restrict__ x_src, const float* __restrict__ x_self,
    const int* __restrict__ rp, const int* __restrict__ csr,
    const float* __restrict__ Wl, const float* __restrict__ bl,
    const float* __restrict__ Wr, float* __restrict__ hout, int n,
    const float* __restrict__ Wout, const float* __restrict__ bout,
    float* __restrict__ head_out) {
  __shared__ float sWl[KL * 64];
  __shared__ float sWr[KR * 64];
  __shared__ float sMean[4][KL];
  const int t = threadIdx.x;
  for (int i = t; i < KL * 64; i += 256) sWl[i] = Wl[i];
  for (int i = t; i < KR * 64; i += 256) sWr[i] = Wr[i];
  __syncthreads();
  const int lane = t & 63;
  const int w = t >> 6;
  const float blj = bl[lane];
  for (int node = blockIdx.x * 4 + w; node < n; node += gridDim.x * 4) {
    // Gather mean: lane holds feature `lane` (and `64+lane` if KL==128).
    const int beg = rp[node], end = rp[node + 1];
    float acc0 = 0.f, acc1 = 0.f;
    for (int base = beg; base < end; base += 64) {
      const int m = min(64, end - base);
      const int kreg = (base + lane < end) ? csr[base + lane] : 0;
      for (int i = 0; i < m; ++i) {
        const int s = __shfl(kreg, i, 64);
        const float* __restrict__ row = x_src + (long long)s * KL;
        acc0 += row[lane];
        if (KL == 128) acc1 += row[64 + lane];
      }
    }
    const float r = 1.0f / fmaxf((float)(end - beg), 1.0f);
    sMean[w][lane] = acc0 * r;
    if (KL == 128) sMean[w][64 + lane] = acc1 * r;
    // Same-wave LDS write->read: compiler orders via lgkmcnt; no barrier.
    float acc = blj;
    const float4* __restrict__ m4 = (const float4*)sMean[w];
#pragma unroll
    for (int k4 = 0; k4 < KL / 4; ++k4) {
      const float4 v = m4[k4];
      acc += v.x * sWl[(k4 * 4 + 0) * 64 + lane];
      acc += v.y * sWl[(k4 * 4 + 1) * 64 + lane];
      acc += v.z * sWl[(k4 * 4 + 2) * 64 + lane];
      acc += v.w * sWl[(k4 * 4 + 3) * 64 + lane];
    }
    const float4* __restrict__ x4 =
        (const float4*)(x_self + (long long)node * KR);
#pragma unroll
    for (int k4 = 0; k4 < KR / 4; ++k4) {
      const float4 v = x4[k4];
      acc += v.x * sWr[(k4 * 4 + 0) * 64 + lane];
      acc += v.y * sWr[(k4 * 4 + 1) * 64 + lane];
      acc += v.z * sWr[(k4 * 4 + 2) * 64 + lane];
      acc += v.w * sWr[(k4 * 4 + 3) * 64 + lane];
    }
    const float h = acc >= 0.f ? acc : 0.01f * acc;
    hout[(long long)node * 64 + lane] = h;
    if (HEAD) {
      float s0 = h * Wout[lane * 2 + 0];
      float s1 = h * Wout[lane * 2 + 1];
#pragma unroll
      for (int off = 32; off > 0; off >>= 1) {
        s0 += __shfl_xor(s0, off, 64);
        s1 += __shfl_xor(s1, off, 64);
      }
      if (lane == 0) {
        head_out[(long long)node * 2 + 0] = s0 + bout[0];
        head_out[(long long)node * 2 + 1] = s1 + bout[1];
      }
    }
  }
}
}  // namespace

extern "C" void kernel_launch(void* const* d_in, const int* in_sizes, int n_in,
                              void* d_out, int out_size, void* d_ws, size_t ws_size,
                              hipStream_t stream) {
  const float* x_trans = (const float*)d_in[0];
  const float* x_merch = (const float*)d_in[1];
  const int* tm_src = (const int*)d_in[2];
  const int* tm_dst = (const int*)d_in[3];
  const int* mt_src = (const int*)d_in[4];
  const int* mt_dst = (const int*)d_in[5];
  const float* Wl_tm1 = (const float*)d_in[6];
  const float* bl_tm1 = (const float*)d_in[7];
  const float* Wr_tm1 = (const float*)d_in[8];
  const float* Wl_mt1 = (const float*)d_in[9];
  const float* bl_mt1 = (const float*)d_in[10];
  const float* Wr_mt1 = (const float*)d_in[11];
  // d_in[12..14]: layer-2 tm weights unused (h_m2 is dead in the reference).
  const float* Wl_mt2 = (const float*)d_in[15];
  const float* bl_mt2 = (const float*)d_in[16];
  const float* Wr_mt2 = (const float*)d_in[17];
  const float* W_out = (const float*)d_in[18];
  const float* b_out = (const float*)d_in[19];

  float* out_head = (float*)d_out;                   // [N_T, 2]
  float* h_t = (float*)d_out + (long long)kNT * 2;   // [N_T, 64]; layer-1 h_t,
                                                     // overwritten in-place with h_t2

  char* ws = (char*)d_ws;
  size_t off = 0;
  auto alloc = [&](size_t bytes) {
    char* p = ws + off;
    off = (off + bytes + 255) & ~(size_t)255;
    return p;
  };
  int* cnt_m = (int*)alloc(kNM * 4);  // also holds scanned values
  int* cnt_t = (int*)alloc(kNT * 4);
  int* rp_m = (int*)alloc((kNM + 1) * 4);
  int* rp_t = (int*)alloc((kNT + 1) * 4);
  int* next_m = (int*)alloc(kNM * 4);
  int* next_t = (int*)alloc(kNT * 4);
  int* part_m = (int*)alloc(256 * 4);
  int* part_t = (int*)alloc(256 * 4);
  int* csr_tm = (int*)alloc((size_t)kE * 4);
  int* csr_mt = (int*)alloc((size_t)kE * 4);
  float* h_m = (float*)alloc((size_t)kNM * 64 * 4);

  // Zero the two count arrays (adjacent at the front of ws).
  hipMemsetAsync(d_ws, 0, (size_t)((char*)(cnt_t + kNT) - ws), stream);

  // CSR build: histogram -> exclusive scan -> slot fill.
  hist_kernel<<<2048, 256, 0, stream>>>(tm_dst, mt_dst, cnt_m, cnt_t);

  const int nbm = (kNM + 1023) / 1024, nbt = (kNT + 1023) / 1024;
  scan_blocks_kernel<<<nbm, 256, 0, stream>>>(cnt_m, kNM, cnt_m, part_m);
  scan_blocks_kernel<<<nbt, 256, 0, stream>>>(cnt_t, kNT, cnt_t, part_t);
  scan_partials_kernel<<<1, 256, 0, stream>>>(part_m, nbm);
  scan_partials_kernel<<<1, 256, 0, stream>>>(part_t, nbt);
  add_offsets_kernel<<<(kNM + 255) / 256, 256, 0, stream>>>(cnt_m, part_m, kNM,
                                                            rp_m, next_m);
  add_offsets_kernel<<<(kNT + 255) / 256, 256, 0, stream>>>(cnt_t, part_t, kNT,
                                                            rp_t, next_t);
  fill_csr_kernel<<<2048, 256, 0, stream>>>(tm_src, tm_dst, next_m, csr_tm);
  fill_csr_kernel<<<2048, 256, 0, stream>>>(mt_src, mt_dst, next_t, csr_mt);

  // Layer 1, merchants: mean over tm edges (x_trans rows) + x_merch self.
  fused_sage_kernel<128, 64, false><<<1024, 256, 0, stream>>>(
      x_trans, x_merch, rp_m, csr_tm, Wl_tm1, bl_tm1, Wr_tm1, h_m, kNM,
      nullptr, nullptr, nullptr);
  // Layer 1, transactions: mean over mt edges (x_merch rows) + x_trans self.
  fused_sage_kernel<64, 128, false><<<2048, 256, 0, stream>>>(
      x_merch, x_trans, rp_t, csr_mt, Wl_mt1, bl_mt1, Wr_mt1, h_t, kNT,
      nullptr, nullptr, nullptr);
  // Layer 2, transactions (+ fused head): mean over mt edges (h_m rows) + h_t.
  fused_sage_kernel<64, 64, true><<<2048, 256, 0, stream>>>(
      h_m, h_t, rp_t, csr_mt, Wl_mt2, bl_mt2, Wr_mt2, h_t, kNT, W_out, b_out,
      out_head);
}

// Round 4
// 983.587 us; speedup vs baseline: 5.7741x; 1.2910x over previous
//
#include <hip/hip_runtime.h>

namespace {
constexpr int kNT = 200000;
constexpr int kNM = 20000;
constexpr int kE  = 1000000;

// --- CSR build ---------------------------------------------------------------

__global__ void hist_kernel(const int* __restrict__ tm_dst,
                            const int* __restrict__ mt_dst,
                            int* __restrict__ cnt_m, int* __restrict__ cnt_t) {
  int stride = gridDim.x * blockDim.x;
  for (int e = blockIdx.x * blockDim.x + threadIdx.x; e < kE; e += stride) {
    atomicAdd(&cnt_m[tm_dst[e]], 1);
    atomicAdd(&cnt_t[mt_dst[e]], 1);
  }
}

// Per-block exclusive scan over chunks of 1024 (256 thr x 4). Safe with out==in.
__global__ __launch_bounds__(256) void scan_blocks_kernel(
    const int* __restrict__ in, int n, int* __restrict__ out,
    int* __restrict__ partials) {
  __shared__ int lds[256];
  const int t = threadIdx.x;
  const int base = blockIdx.x * 1024;
  int v[4];
  int s = 0;
#pragma unroll
  for (int k = 0; k < 4; ++k) {
    int idx = base + t * 4 + k;
    v[k] = (idx < n) ? in[idx] : 0;
    s += v[k];
  }
  int x = s;
  lds[t] = x;
  __syncthreads();
  for (int off = 1; off < 256; off <<= 1) {
    int y = (t >= off) ? lds[t - off] : 0;
    __syncthreads();
    x += y;
    lds[t] = x;
    __syncthreads();
  }
  if (t == 255) partials[blockIdx.x] = x;
  int run = x - s;  // exclusive prefix of this thread's chunk
#pragma unroll
  for (int k = 0; k < 4; ++k) {
    int idx = base + t * 4 + k;
    if (idx < n) out[idx] = run;
    run += v[k];
  }
}

// Single block; nb <= 256. In-place inclusive->exclusive scan of block totals.
__global__ __launch_bounds__(256) void scan_partials_kernel(int* __restrict__ p,
                                                            int nb) {
  __shared__ int lds[256];
  const int t = threadIdx.x;
  int v = (t < nb) ? p[t] : 0;
  int x = v;
  lds[t] = x;
  __syncthreads();
  for (int off = 1; off < 256; off <<= 1) {
    int y = (t >= off) ? lds[t - off] : 0;
    __syncthreads();
    x += y;
    lds[t] = x;
    __syncthreads();
  }
  if (t < nb) p[t] = x - v;
}

__global__ void add_offsets_kernel(const int* __restrict__ scanned,
                                   const int* __restrict__ partials, int n,
                                   int* __restrict__ rp, int* __restrict__ next) {
  int i = blockIdx.x * 256 + threadIdx.x;
  if (i == 0) rp[n] = kE;
  if (i < n) {
    int v = scanned[i] + partials[i >> 10];
    rp[i] = v;
    next[i] = v;
  }
}

__global__ void fill_csr_kernel(const int* __restrict__ src,
                                const int* __restrict__ dst,
                                int* __restrict__ next, int* __restrict__ csr) {
  int stride = gridDim.x * blockDim.x;
  for (int e = blockIdx.x * blockDim.x + threadIdx.x; e < kE; e += stride) {
    int p = atomicAdd(&next[dst[e]], 1);
    csr[p] = src[e];
  }
}

// --- Fused SAGE layer: gather-mean + lin_l + lin_r + lrelu (+head) -----------
// One wave per dst node; persistent blocks (weights staged once per block).
// Gather uses a (slot, f4) lane layout: SLOTS neighbors read in parallel with
// float4 loads, unrolled x4 -> up to 4*SLOTS independent loads in flight.
// Partial sums reduced across slots via shfl_xor butterfly, parked in per-wave
// LDS; self row read coalesced and parked too. FMA loop then runs entirely on
// LDS broadcasts (conflict-free) + staged weights (2-way alias, free).
template <int KL, int KR, bool HEAD>
__global__ __launch_bounds__(256) void fused_sage_kernel(
    const float* __restrict__ x_src, const float* __restrict__ x_self,
    const int* __restrict__ rp, const int* __restrict__ csr,
    const float* __restrict__ Wl, const float* __restrict__ bl,
    const float* __restrict__ Wr, float* __restrict__ hout, int n,
    const float* __restrict__ Wout, const float* __restrict__ bout,
    float* __restrict__ head_out) {
  __shared__ float sWl[KL * 64];
  __shared__ float sWr[KR * 64];
  __shared__ float sMean[4][KL];
  __shared__ float sSelf[4][KR];
  const int t = threadIdx.x;
  for (int i = t; i < KL * 64; i += 256) sWl[i] = Wl[i];
  for (int i = t; i < KR * 64; i += 256) sWr[i] = Wr[i];
  __syncthreads();
  const int lane = t & 63;
  const int w = t >> 6;
  constexpr int F4 = KL / 4;      // float4s per source row
  constexpr int SLOTS = 64 / F4;  // neighbors gathered in parallel (4 or 2)
  const int f4 = lane & (F4 - 1);
  const int slot = lane / F4;
  const float blj = bl[lane];
  for (int node = blockIdx.x * 4 + w; node < n; node += gridDim.x * 4) {
    // Self row: coalesced load, issued early.
    const float self0 = x_self[(long long)node * KR + lane];
    const float self1 =
        (KR == 128) ? x_self[(long long)node * KR + 64 + lane] : 0.f;
    const int beg = rp[node], end = rp[node + 1];
    float ax = 0.f, ay = 0.f, az = 0.f, aw = 0.f;
    for (int base = beg; base < end; base += 4 * SLOTS) {
#pragma unroll
      for (int u = 0; u < 4; ++u) {
        const int e = base + u * SLOTS + slot;
        if (e < end) {
          const int s = csr[e];
          const float4 v =
              ((const float4*)(x_src + (long long)s * KL))[f4];
          ax += v.x;
          ay += v.y;
          az += v.z;
          aw += v.w;
        }
      }
    }
    // Reduce across slot bits (lane bits >= log2(F4)).
#pragma unroll
    for (int off = F4; off < 64; off <<= 1) {
      ax += __shfl_xor(ax, off, 64);
      ay += __shfl_xor(ay, off, 64);
      az += __shfl_xor(az, off, 64);
      aw += __shfl_xor(aw, off, 64);
    }
    const float r = 1.0f / fmaxf((float)(end - beg), 1.0f);
    if (lane < F4) {
      float4* m4 = (float4*)sMean[w];
      m4[f4] = make_float4(ax * r, ay * r, az * r, aw * r);
    }
    sSelf[w][lane] = self0;
    if (KR == 128) sSelf[w][64 + lane] = self1;
    // Same-wave LDS write->read: ordered via lgkmcnt; no barrier needed.
    float acc = blj;
    const float4* __restrict__ m4 = (const float4*)sMean[w];
    const float4* __restrict__ s4 = (const float4*)sSelf[w];
#pragma unroll
    for (int k4 = 0; k4 < KL / 4; ++k4) {
      const float4 v = m4[k4];
      acc += v.x * sWl[(k4 * 4 + 0) * 64 + lane];
      acc += v.y * sWl[(k4 * 4 + 1) * 64 + lane];
      acc += v.z * sWl[(k4 * 4 + 2) * 64 + lane];
      acc += v.w * sWl[(k4 * 4 + 3) * 64 + lane];
    }
#pragma unroll
    for (int k4 = 0; k4 < KR / 4; ++k4) {
      const float4 v = s4[k4];
      acc += v.x * sWr[(k4 * 4 + 0) * 64 + lane];
      acc += v.y * sWr[(k4 * 4 + 1) * 64 + lane];
      acc += v.z * sWr[(k4 * 4 + 2) * 64 + lane];
      acc += v.w * sWr[(k4 * 4 + 3) * 64 + lane];
    }
    const float h = acc >= 0.f ? acc : 0.01f * acc;
    hout[(long long)node * 64 + lane] = h;
    if (HEAD) {
      float s0 = h * Wout[lane * 2 + 0];
      float s1 = h * Wout[lane * 2 + 1];
#pragma unroll
      for (int off = 32; off > 0; off >>= 1) {
        s0 += __shfl_xor(s0, off, 64);
        s1 += __shfl_xor(s1, off, 64);
      }
      if (lane == 0) {
        head_out[(long long)node * 2 + 0] = s0 + bout[0];
        head_out[(long long)node * 2 + 1] = s1 + bout[1];
      }
    }
  }
}
}  // namespace

extern "C" void kernel_launch(void* const* d_in, const int* in_sizes, int n_in,
                              void* d_out, int out_size, void* d_ws, size_t ws_size,
                              hipStream_t stream) {
  const float* x_trans = (const float*)d_in[0];
  const float* x_merch = (const float*)d_in[1];
  const int* tm_src = (const int*)d_in[2];
  const int* tm_dst = (const int*)d_in[3];
  const int* mt_src = (const int*)d_in[4];
  const int* mt_dst = (const int*)d_in[5];
  const float* Wl_tm1 = (const float*)d_in[6];
  const float* bl_tm1 = (const float*)d_in[7];
  const float* Wr_tm1 = (const float*)d_in[8];
  const float* Wl_mt1 = (const float*)d_in[9];
  const float* bl_mt1 = (const float*)d_in[10];
  const float* Wr_mt1 = (const float*)d_in[11];
  // d_in[12..14]: layer-2 tm weights unused (h_m2 is dead in the reference).
  const float* Wl_mt2 = (const float*)d_in[15];
  const float* bl_mt2 = (const float*)d_in[16];
  const float* Wr_mt2 = (const float*)d_in[17];
  const float* W_out = (const float*)d_in[18];
  const float* b_out = (const float*)d_in[19];

  float* out_head = (float*)d_out;                   // [N_T, 2]
  float* h_t = (float*)d_out + (long long)kNT * 2;   // [N_T, 64]; layer-1 h_t,
                                                     // overwritten in-place with h_t2

  char* ws = (char*)d_ws;
  size_t off = 0;
  auto alloc = [&](size_t bytes) {
    char* p = ws + off;
    off = (off + bytes + 255) & ~(size_t)255;
    return p;
  };
  int* cnt_m = (int*)alloc(kNM * 4);  // also holds scanned values
  int* cnt_t = (int*)alloc(kNT * 4);
  int* rp_m = (int*)alloc((kNM + 1) * 4);
  int* rp_t = (int*)alloc((kNT + 1) * 4);
  int* next_m = (int*)alloc(kNM * 4);
  int* next_t = (int*)alloc(kNT * 4);
  int* part_m = (int*)alloc(256 * 4);
  int* part_t = (int*)alloc(256 * 4);
  int* csr_tm = (int*)alloc((size_t)kE * 4);
  int* csr_mt = (int*)alloc((size_t)kE * 4);
  float* h_m = (float*)alloc((size_t)kNM * 64 * 4);

  // Zero the two count arrays (adjacent at the front of ws).
  hipMemsetAsync(d_ws, 0, (size_t)((char*)(cnt_t + kNT) - ws), stream);

  // CSR build: histogram -> exclusive scan -> slot fill.
  hist_kernel<<<2048, 256, 0, stream>>>(tm_dst, mt_dst, cnt_m, cnt_t);

  const int nbm = (kNM + 1023) / 1024, nbt = (kNT + 1023) / 1024;
  scan_blocks_kernel<<<nbm, 256, 0, stream>>>(cnt_m, kNM, cnt_m, part_m);
  scan_blocks_kernel<<<nbt, 256, 0, stream>>>(cnt_t, kNT, cnt_t, part_t);
  scan_partials_kernel<<<1, 256, 0, stream>>>(part_m, nbm);
  scan_partials_kernel<<<1, 256, 0, stream>>>(part_t, nbt);
  add_offsets_kernel<<<(kNM + 255) / 256, 256, 0, stream>>>(cnt_m, part_m, kNM,
                                                            rp_m, next_m);
  add_offsets_kernel<<<(kNT + 255) / 256, 256, 0, stream>>>(cnt_t, part_t, kNT,
                                                            rp_t, next_t);
  fill_csr_kernel<<<2048, 256, 0, stream>>>(tm_src, tm_dst, next_m, csr_tm);
  fill_csr_kernel<<<2048, 256, 0, stream>>>(mt_src, mt_dst, next_t, csr_mt);

  // Layer 1, merchants: mean over tm edges (x_trans rows) + x_merch self.
  fused_sage_kernel<128, 64, false><<<1024, 256, 0, stream>>>(
      x_trans, x_merch, rp_m, csr_tm, Wl_tm1, bl_tm1, Wr_tm1, h_m, kNM,
      nullptr, nullptr, nullptr);
  // Layer 1, transactions: mean over mt edges (x_merch rows) + x_trans self.
  fused_sage_kernel<64, 128, false><<<2048, 256, 0, stream>>>(
      x_merch, x_trans, rp_t, csr_mt, Wl_mt1, bl_mt1, Wr_mt1, h_t, kNT,
      nullptr, nullptr, nullptr);
  // Layer 2, transactions (+ fused head): mean over mt edges (h_m rows) + h_t.
  fused_sage_kernel<64, 64, true><<<2048, 256, 0, stream>>>(
      h_m, h_t, rp_t, csr_mt, Wl_mt2, bl_mt2, Wr_mt2, h_t, kNT, W_out, b_out,
      out_head);
}